// Round 5
// baseline (24.743 us; speedup 1.0000x reference)
//
#include <hip/hip_runtime.h>
#include <hip/hip_fp16.h>

// bg: (1,4,32,32,32,16) f32 ; gm: (1,1,128,128,128) f32 ; out: (1,4,128,128,128) f32
//
// Two-kernel scheme:
//  k1: repack bg (channel-planar f32) -> ws (node-AoS fp16). Per (node,s) a
//      16B record: {t=s: c0c1,c2c3 | t=s+1: c0c1,c2c3}. 32768 nodes * 256B = 8MB.
//  k2: per block tile 8(i) x 8(j) x 16(k); stage 96 nodes (4x*4y*6z) * 16 slots
//      = 24KB into LDS via global_load_lds dwordx4 (layout matches ws exactly),
//      then quadrilinear interp: 8 x ds_read_b128 per voxel + fp16 xy-accum.

#define S_ (31.0f / 127.0f)
#define CH_STRIDE 524288
#define TOTAL 2097152

#define NX 4
#define NY 4
#define NZ 6
#define NNODES (NX * NY * NZ)          // 96
#define NODE_DW 64                     // dwords per node in ws/LDS (16 slots * 16B)
#define LDS_DW (NNODES * NODE_DW)      // 6144 dwords = 24576 B
#define WS_BYTES (32768 * 256)         // 8 MB

typedef __attribute__((address_space(3))) void lds_void_t;
typedef const __attribute__((address_space(1))) void gbl_void_t;

// ---------------- k1: repack ----------------
__global__ __launch_bounds__(256) void bgrid_repack(
    const float* __restrict__ bg, float* __restrict__ ws)
{
    const int u = blockIdx.x * 256 + threadIdx.x;   // u = node*16 + s
    const int s = u & 15;

    const float c0 = bg[u];
    const float c1 = bg[u + CH_STRIDE];
    const float c2 = bg[u + 2 * CH_STRIDE];
    const float c3 = bg[u + 3 * CH_STRIDE];

    float2 pk;
    pk.x = __builtin_bit_cast(float, __floats2half2_rn(c0, c1));
    pk.y = __builtin_bit_cast(float, __floats2half2_rn(c2, c3));

    const int nb = (u >> 4) << 6;          // node * 64 dwords
    const int sl = nb + (s << 2);
    *(float2*)&ws[sl] = pk;                // lo of slot s
    if (s > 0) *(float2*)&ws[sl - 2] = pk; // hi of slot s-1  (sl-4+2)
    // slot 15's hi half is never read (t0 <= 14), leave unwritten.
}

// ---------------- k2: slice ----------------
__global__ __launch_bounds__(256) void bgrid_slice_v5(
    const float* __restrict__ ws,
    const float* __restrict__ gm,
    float* __restrict__ out)
{
    __shared__ __align__(16) float lds[LDS_DW];

    const int tid = threadIdx.x;
    // XCD-chunked swizzle: 2048 blocks, 8 XCDs -> 256-tile contiguous chunks.
    const int b = blockIdx.x;
    const int tile = ((b & 7) << 8) + (b >> 3);
    const int bk = tile & 7;
    const int bj = (tile >> 3) & 15;
    const int bi = tile >> 7;

    const int i0 = bi * 8, j0 = bj * 8, k0 = bk * 16;
    const int x_base = (int)((float)i0 * S_);
    const int y_base = (int)((float)j0 * S_);
    const int z_base = (int)((float)k0 * S_);

    // ---- stage: 96 nodes * 16 slots = 1536 records of 16B, 6 per thread ----
    const char* wsb = (const char*)ws;
    #pragma unroll
    for (int it = 0; it < 6; ++it) {
        const int q = tid + it * 256;
        const int n = q >> 4;
        const int s = q & 15;
        const int a = n / (NY * NZ);
        const int rem = n - a * (NY * NZ);
        const int bb = rem / NZ;
        const int cz = rem - bb * NZ;
        const int gx = min(x_base + a, 31);
        const int gy = min(y_base + bb, 31);
        const int gz = min(z_base + cz, 31);
        gbl_void_t* src = (gbl_void_t*)(wsb + ((((gx * 32 + gy) * 32 + gz) << 8) + (s << 4)));
        __builtin_amdgcn_global_load_lds(src, (lds_void_t*)&lds[q << 2], 16, 0, 0);
    }
    __syncthreads();

    // ---- interp: thread = (li, lj, kq); voxels k = k0+kq*4 .. +3 ----
    const int kq = tid & 3;
    const int lj = (tid >> 2) & 7;
    const int li = tid >> 5;
    const int i = i0 + li, j = j0 + lj;
    const int kk = k0 + (kq << 2);

    const float xf = fminf((float)i * S_, 31.0f);
    const float yf = fminf((float)j * S_, 31.0f);
    const int x0g = (int)xf; const float fx = xf - (float)x0g;
    const int y0g = (int)yf; const float fy = yf - (float)y0g;
    const int xi0 = x0g - x_base, xi1 = min(x0g + 1, 31) - x_base;
    const int yi0 = y0g - y_base, yi1 = min(y0g + 1, 31) - y_base;

    const int AX0 = xi0 * (NY * NZ * NODE_DW);
    const int AX1 = xi1 * (NY * NZ * NODE_DW);
    const int BY0 = yi0 * (NZ * NODE_DW);
    const int BY1 = yi1 * (NZ * NODE_DW);

    const float wx1 = fx, wx0 = 1.0f - fx;
    const float wy1 = fy, wy0 = 1.0f - fy;
    const __half2 W00 = __float2half2_rn(wx0 * wy0);
    const __half2 W01 = __float2half2_rn(wx0 * wy1);
    const __half2 W10 = __float2half2_rn(wx1 * wy0);
    const __half2 W11 = __float2half2_rn(wx1 * wy1);

    const int idx = (i << 14) | (j << 7) | kk;
    const float4 g4 = *(const float4*)&gm[idx];

    float o0[4], o1[4], o2[4], o3[4];

#pragma unroll
    for (int v = 0; v < 4; ++v) {
        const float g = (v == 0) ? g4.x : (v == 1) ? g4.y : (v == 2) ? g4.z : g4.w;
        float t = fminf(fmaxf(g * 15.0f, 0.0f), 15.0f);
        const int t0 = min((int)t, 14);
        const float ft = t - (float)t0;
        const __half2 ft2 = __float2half2_rn(ft);

        const float zf = fminf((float)(kk + v) * S_, 31.0f);
        const int z0g = (int)zf;
        const float fz = zf - (float)z0g;
        const int zi0 = z0g - z_base;
        const int zi1 = min(z0g + 1, 31) - z_base;
        const __half2 fz2 = __float2half2_rn(fz);

        const int CZ0 = zi0 * NODE_DW + (t0 << 2);
        const int CZ1 = zi1 * NODE_DW + (t0 << 2);

        const float4 a00 = *(const float4*)&lds[AX0 + BY0 + CZ0];
        const float4 a01 = *(const float4*)&lds[AX0 + BY1 + CZ0];
        const float4 a10 = *(const float4*)&lds[AX1 + BY0 + CZ0];
        const float4 a11 = *(const float4*)&lds[AX1 + BY1 + CZ0];
        const float4 b00 = *(const float4*)&lds[AX0 + BY0 + CZ1];
        const float4 b01 = *(const float4*)&lds[AX0 + BY1 + CZ1];
        const float4 b10 = *(const float4*)&lds[AX1 + BY0 + CZ1];
        const float4 b11 = *(const float4*)&lds[AX1 + BY1 + CZ1];

#define H2(f) __builtin_bit_cast(__half2, f)
        __half2 Plo01 = __hmul2(W00, H2(a00.x));
        __half2 Plo23 = __hmul2(W00, H2(a00.y));
        __half2 Phi01 = __hmul2(W00, H2(a00.z));
        __half2 Phi23 = __hmul2(W00, H2(a00.w));
        Plo01 = __hfma2(W01, H2(a01.x), Plo01);
        Plo23 = __hfma2(W01, H2(a01.y), Plo23);
        Phi01 = __hfma2(W01, H2(a01.z), Phi01);
        Phi23 = __hfma2(W01, H2(a01.w), Phi23);
        Plo01 = __hfma2(W10, H2(a10.x), Plo01);
        Plo23 = __hfma2(W10, H2(a10.y), Plo23);
        Phi01 = __hfma2(W10, H2(a10.z), Phi01);
        Phi23 = __hfma2(W10, H2(a10.w), Phi23);
        Plo01 = __hfma2(W11, H2(a11.x), Plo01);
        Plo23 = __hfma2(W11, H2(a11.y), Plo23);
        Phi01 = __hfma2(W11, H2(a11.z), Phi01);
        Phi23 = __hfma2(W11, H2(a11.w), Phi23);

        __half2 Qlo01 = __hmul2(W00, H2(b00.x));
        __half2 Qlo23 = __hmul2(W00, H2(b00.y));
        __half2 Qhi01 = __hmul2(W00, H2(b00.z));
        __half2 Qhi23 = __hmul2(W00, H2(b00.w));
        Qlo01 = __hfma2(W01, H2(b01.x), Qlo01);
        Qlo23 = __hfma2(W01, H2(b01.y), Qlo23);
        Qhi01 = __hfma2(W01, H2(b01.z), Qhi01);
        Qhi23 = __hfma2(W01, H2(b01.w), Qhi23);
        Qlo01 = __hfma2(W10, H2(b10.x), Qlo01);
        Qlo23 = __hfma2(W10, H2(b10.y), Qlo23);
        Qhi01 = __hfma2(W10, H2(b10.z), Qhi01);
        Qhi23 = __hfma2(W10, H2(b10.w), Qhi23);
        Qlo01 = __hfma2(W11, H2(b11.x), Qlo01);
        Qlo23 = __hfma2(W11, H2(b11.y), Qlo23);
        Qhi01 = __hfma2(W11, H2(b11.z), Qhi01);
        Qhi23 = __hfma2(W11, H2(b11.w), Qhi23);
#undef H2

        const __half2 Rlo01 = __hfma2(fz2, __hsub2(Qlo01, Plo01), Plo01);
        const __half2 Rlo23 = __hfma2(fz2, __hsub2(Qlo23, Plo23), Plo23);
        const __half2 Rhi01 = __hfma2(fz2, __hsub2(Qhi01, Phi01), Phi01);
        const __half2 Rhi23 = __hfma2(fz2, __hsub2(Qhi23, Phi23), Phi23);

        const __half2 r01 = __hfma2(ft2, __hsub2(Rhi01, Rlo01), Rlo01);
        const __half2 r23 = __hfma2(ft2, __hsub2(Rhi23, Rlo23), Rlo23);

        o0[v] = __low2float(r01);
        o1[v] = __high2float(r01);
        o2[v] = __low2float(r23);
        o3[v] = __high2float(r23);
    }

    float4 st;
    st.x = o0[0]; st.y = o0[1]; st.z = o0[2]; st.w = o0[3];
    *(float4*)&out[idx] = st;
    st.x = o1[0]; st.y = o1[1]; st.z = o1[2]; st.w = o1[3];
    *(float4*)&out[idx + TOTAL] = st;
    st.x = o2[0]; st.y = o2[1]; st.z = o2[2]; st.w = o2[3];
    *(float4*)&out[idx + 2 * TOTAL] = st;
    st.x = o3[0]; st.y = o3[1]; st.z = o3[2]; st.w = o3[3];
    *(float4*)&out[idx + 3 * TOTAL] = st;
}

// ---------------- fallback: proven single-kernel v4 (if ws too small) ----------------
#define FNODE_DW 68
__global__ __launch_bounds__(256, 5) void bgrid_slice_fb(
    const float* __restrict__ bg,
    const float* __restrict__ gm,
    float* __restrict__ out)
{
    __shared__ __align__(16) float lds[NNODES * FNODE_DW];

    const int tid = threadIdx.x;
    const int b = blockIdx.x;
    const int bk = b & 7;
    const int bj = (b >> 3) & 15;
    const int bi = b >> 7;

    const int i0 = bi * 8, j0 = bj * 8, k0 = bk * 16;
    const int x_base = (int)((float)i0 * S_);
    const int y_base = (int)((float)j0 * S_);
    const int z_base = (int)((float)k0 * S_);

    for (int q = tid; q < NNODES * 16; q += 256) {
        const int node = q >> 4;
        const int s = q & 15;
        const int a = node / (NY * NZ);
        const int rem = node - a * (NY * NZ);
        const int bb = rem / NZ;
        const int cz = rem - bb * NZ;
        const int gx = min(x_base + a, 31);
        const int gy = min(y_base + bb, 31);
        const int gz = min(z_base + cz, 31);
        const int gbase = (((gx * 32 + gy) * 32 + gz) << 4) + s;

        const float c0 = bg[gbase];
        const float c1 = bg[gbase + CH_STRIDE];
        const float c2 = bg[gbase + 2 * CH_STRIDE];
        const float c3 = bg[gbase + 3 * CH_STRIDE];

        float2 pk;
        pk.x = __builtin_bit_cast(float, __floats2half2_rn(c0, c1));
        pk.y = __builtin_bit_cast(float, __floats2half2_rn(c2, c3));

        const int nb = node * FNODE_DW;
        *(float2*)&lds[nb + (s << 2)] = pk;
        if (s > 0)  *(float2*)&lds[nb + ((s - 1) << 2) + 2] = pk;
        if (s == 15) *(float2*)&lds[nb + (15 << 2) + 2] = pk;
    }
    __syncthreads();

    const int kq = tid & 3;
    const int lj = (tid >> 2) & 7;
    const int li = tid >> 5;
    const int i = i0 + li, j = j0 + lj;
    const int kk = k0 + (kq << 2);

    const float xf = fminf((float)i * S_, 31.0f);
    const float yf = fminf((float)j * S_, 31.0f);
    const int x0g = (int)xf; const float fx = xf - (float)x0g;
    const int y0g = (int)yf; const float fy = yf - (float)y0g;
    const int xi0 = x0g - x_base, xi1 = min(x0g + 1, 31) - x_base;
    const int yi0 = y0g - y_base, yi1 = min(y0g + 1, 31) - y_base;

    const int AX0 = xi0 * (NY * NZ * FNODE_DW);
    const int AX1 = xi1 * (NY * NZ * FNODE_DW);
    const int BY0 = yi0 * (NZ * FNODE_DW);
    const int BY1 = yi1 * (NZ * FNODE_DW);

    const float wx1 = fx, wx0 = 1.0f - fx;
    const float wy1 = fy, wy0 = 1.0f - fy;
    const __half2 W00 = __float2half2_rn(wx0 * wy0);
    const __half2 W01 = __float2half2_rn(wx0 * wy1);
    const __half2 W10 = __float2half2_rn(wx1 * wy0);
    const __half2 W11 = __float2half2_rn(wx1 * wy1);

    const int idx = (i << 14) | (j << 7) | kk;
    const float4 g4 = *(const float4*)&gm[idx];

    float o0[4], o1[4], o2[4], o3[4];

#pragma unroll
    for (int v = 0; v < 4; ++v) {
        const float g = (v == 0) ? g4.x : (v == 1) ? g4.y : (v == 2) ? g4.z : g4.w;
        float t = fminf(fmaxf(g * 15.0f, 0.0f), 15.0f);
        const int t0 = min((int)t, 14);
        const float ft = t - (float)t0;
        const __half2 ft2 = __float2half2_rn(ft);

        const float zf = fminf((float)(kk + v) * S_, 31.0f);
        const int z0g = (int)zf;
        const float fz = zf - (float)z0g;
        const int zi0 = z0g - z_base;
        const int zi1 = min(z0g + 1, 31) - z_base;
        const __half2 fz2 = __float2half2_rn(fz);

        const int CZ0 = zi0 * FNODE_DW + (t0 << 2);
        const int CZ1 = zi1 * FNODE_DW + (t0 << 2);

        const float4 a00 = *(const float4*)&lds[AX0 + BY0 + CZ0];
        const float4 a01 = *(const float4*)&lds[AX0 + BY1 + CZ0];
        const float4 a10 = *(const float4*)&lds[AX1 + BY0 + CZ0];
        const float4 a11 = *(const float4*)&lds[AX1 + BY1 + CZ0];
        const float4 b00 = *(const float4*)&lds[AX0 + BY0 + CZ1];
        const float4 b01 = *(const float4*)&lds[AX0 + BY1 + CZ1];
        const float4 b10 = *(const float4*)&lds[AX1 + BY0 + CZ1];
        const float4 b11 = *(const float4*)&lds[AX1 + BY1 + CZ1];

#define H2(f) __builtin_bit_cast(__half2, f)
        __half2 Plo01 = __hmul2(W00, H2(a00.x));
        __half2 Plo23 = __hmul2(W00, H2(a00.y));
        __half2 Phi01 = __hmul2(W00, H2(a00.z));
        __half2 Phi23 = __hmul2(W00, H2(a00.w));
        Plo01 = __hfma2(W01, H2(a01.x), Plo01);
        Plo23 = __hfma2(W01, H2(a01.y), Plo23);
        Phi01 = __hfma2(W01, H2(a01.z), Phi01);
        Phi23 = __hfma2(W01, H2(a01.w), Phi23);
        Plo01 = __hfma2(W10, H2(a10.x), Plo01);
        Plo23 = __hfma2(W10, H2(a10.y), Plo23);
        Phi01 = __hfma2(W10, H2(a10.z), Phi01);
        Phi23 = __hfma2(W10, H2(a10.w), Phi23);
        Plo01 = __hfma2(W11, H2(a11.x), Plo01);
        Plo23 = __hfma2(W11, H2(a11.y), Plo23);
        Phi01 = __hfma2(W11, H2(a11.z), Phi01);
        Phi23 = __hfma2(W11, H2(a11.w), Phi23);

        __half2 Qlo01 = __hmul2(W00, H2(b00.x));
        __half2 Qlo23 = __hmul2(W00, H2(b00.y));
        __half2 Qhi01 = __hmul2(W00, H2(b00.z));
        __half2 Qhi23 = __hmul2(W00, H2(b00.w));
        Qlo01 = __hfma2(W01, H2(b01.x), Qlo01);
        Qlo23 = __hfma2(W01, H2(b01.y), Qlo23);
        Qhi01 = __hfma2(W01, H2(b01.z), Qhi01);
        Qhi23 = __hfma2(W01, H2(b01.w), Qhi23);
        Qlo01 = __hfma2(W10, H2(b10.x), Qlo01);
        Qlo23 = __hfma2(W10, H2(b10.y), Qlo23);
        Qhi01 = __hfma2(W10, H2(b10.z), Qhi01);
        Qhi23 = __hfma2(W10, H2(b10.w), Qhi23);
        Qlo01 = __hfma2(W11, H2(b11.x), Qlo01);
        Qlo23 = __hfma2(W11, H2(b11.y), Qlo23);
        Qhi01 = __hfma2(W11, H2(b11.z), Qhi01);
        Qhi23 = __hfma2(W11, H2(b11.w), Qhi23);
#undef H2

        const __half2 Rlo01 = __hfma2(fz2, __hsub2(Qlo01, Plo01), Plo01);
        const __half2 Rlo23 = __hfma2(fz2, __hsub2(Qlo23, Plo23), Plo23);
        const __half2 Rhi01 = __hfma2(fz2, __hsub2(Qhi01, Phi01), Phi01);
        const __half2 Rhi23 = __hfma2(fz2, __hsub2(Qhi23, Phi23), Phi23);

        const __half2 r01 = __hfma2(ft2, __hsub2(Rhi01, Rlo01), Rlo01);
        const __half2 r23 = __hfma2(ft2, __hsub2(Rhi23, Rlo23), Rlo23);

        o0[v] = __low2float(r01);
        o1[v] = __high2float(r01);
        o2[v] = __low2float(r23);
        o3[v] = __high2float(r23);
    }

    float4 st;
    st.x = o0[0]; st.y = o0[1]; st.z = o0[2]; st.w = o0[3];
    *(float4*)&out[idx] = st;
    st.x = o1[0]; st.y = o1[1]; st.z = o1[2]; st.w = o1[3];
    *(float4*)&out[idx + TOTAL] = st;
    st.x = o2[0]; st.y = o2[1]; st.z = o2[2]; st.w = o2[3];
    *(float4*)&out[idx + 2 * TOTAL] = st;
    st.x = o3[0]; st.y = o3[1]; st.z = o3[2]; st.w = o3[3];
    *(float4*)&out[idx + 3 * TOTAL] = st;
}

extern "C" void kernel_launch(void* const* d_in, const int* in_sizes, int n_in,
                              void* d_out, int out_size, void* d_ws, size_t ws_size,
                              hipStream_t stream) {
    const float* bg = (const float*)d_in[0];
    const float* gm = (const float*)d_in[1];
    float* out = (float*)d_out;

    if (ws_size >= (size_t)WS_BYTES) {
        float* ws = (float*)d_ws;
        bgrid_repack<<<dim3(2048), dim3(256), 0, stream>>>(bg, ws);
        bgrid_slice_v5<<<dim3(2048), dim3(256), 0, stream>>>(ws, gm, out);
    } else {
        bgrid_slice_fb<<<dim3(2048), dim3(256), 0, stream>>>(bg, gm, out);
    }
}

// Round 7
// 21.028 us; speedup vs baseline: 1.1767x; 1.1767x over previous
//
#include <hip/hip_runtime.h>
#include <hip/hip_fp16.h>

// bg: (1,4,32,32,32,16) f32 ; gm: (1,1,128,128,128) f32 ; out: (1,4,128,128,128) f32
//
// Single kernel, v4-proven tiling: 8(i) x 8(j) x 16(k) per 256-thread block,
// 4 consecutive k per thread. Staged nodes: 4(x) x 4(y) x 6(z) = 96.
// LDS layout: [node][16 t][4 ch] fp16 (no duplication): per-t record = 8B
// {h2(c0,c1), h2(c2,c3)}; t0 and t0+1 adjacent -> two ds_read_b64 per corner.
// Node stride 36 dwords (144 B, 16B aligned). LDS = 96*144 = 13824 B.
// Staging: item = (node, seg of 4 t): 4x global_load_dwordx4 -> pack -> 2x
// ds_write_b128 (consecutive items hit consecutive bank groups).

#define S_ (31.0f / 127.0f)
#define CH_STRIDE 524288
#define TOTAL 2097152

#define NX 4
#define NY 4
#define NZ 6
#define NNODES (NX * NY * NZ)      // 96
#define NODE_DW 36                 // 32 data dwords + 4 pad
#define LDS_DW (NNODES * NODE_DW)  // 3456 dwords = 13824 B

__global__ __launch_bounds__(256, 6) void bgrid_slice_v7(
    const float* __restrict__ bg,
    const float* __restrict__ gm,
    float* __restrict__ out)
{
    __shared__ __align__(16) float lds[LDS_DW];

    const int tid = threadIdx.x;
    // XCD-chunked swizzle: 2048 blocks, 8 XCDs -> 256-tile contiguous chunks.
    const int b = blockIdx.x;
    const int tile = ((b & 7) << 8) + (b >> 3);
    const int bk = tile & 7;
    const int bj = (tile >> 3) & 15;
    const int bi = tile >> 7;

    const int i0 = bi * 8, j0 = bj * 8, k0 = bk * 16;
    const int x_base = (int)((float)i0 * S_);
    const int y_base = (int)((float)j0 * S_);
    const int z_base = (int)((float)k0 * S_);

    // ---- stage: 96 nodes * 4 segs = 384 items ----
    #pragma unroll
    for (int it = 0; it < 2; ++it) {
        const int q = tid + it * 256;
        if (q < NNODES * 4) {
            const int s4 = q & 3;            // which 4-t segment
            const int node = q >> 2;         // 0..95
            const int a = node / (NY * NZ);
            const int rem = node - a * (NY * NZ);
            const int bb = rem / NZ;
            const int cz = rem - bb * NZ;
            const int gx = min(x_base + a, 31);
            const int gy = min(y_base + bb, 31);
            const int gz = min(z_base + cz, 31);
            const int gbase = (((gx * 32 + gy) * 32 + gz) << 4) + (s4 << 2);

            const float4 L0 = *(const float4*)&bg[gbase];
            const float4 L1 = *(const float4*)&bg[gbase + CH_STRIDE];
            const float4 L2 = *(const float4*)&bg[gbase + 2 * CH_STRIDE];
            const float4 L3 = *(const float4*)&bg[gbase + 3 * CH_STRIDE];

#define PK(x, y) __builtin_bit_cast(float, __floats2half2_rn((x), (y)))
            float4 W0, W1;
            W0.x = PK(L0.x, L1.x); W0.y = PK(L2.x, L3.x);   // t = 4*s4+0
            W0.z = PK(L0.y, L1.y); W0.w = PK(L2.y, L3.y);   // t = 4*s4+1
            W1.x = PK(L0.z, L1.z); W1.y = PK(L2.z, L3.z);   // t = 4*s4+2
            W1.z = PK(L0.w, L1.w); W1.w = PK(L2.w, L3.w);   // t = 4*s4+3
#undef PK
            const int d = node * NODE_DW + (s4 << 3);
            *(float4*)&lds[d] = W0;
            *(float4*)&lds[d + 4] = W1;
        }
    }
    __syncthreads();

    // ---- interp: thread = (li, lj, kq); voxels k = k0+kq*4 .. +3 ----
    const int kq = tid & 3;
    const int lj = (tid >> 2) & 7;
    const int li = tid >> 5;
    const int i = i0 + li, j = j0 + lj;
    const int kk = k0 + (kq << 2);

    const float xf = fminf((float)i * S_, 31.0f);
    const float yf = fminf((float)j * S_, 31.0f);
    const int x0g = (int)xf; const float fx = xf - (float)x0g;
    const int y0g = (int)yf; const float fy = yf - (float)y0g;
    const int xi0 = x0g - x_base, xi1 = min(x0g + 1, 31) - x_base;
    const int yi0 = y0g - y_base, yi1 = min(y0g + 1, 31) - y_base;

    const int AX0 = xi0 * (NY * NZ * NODE_DW);
    const int AX1 = xi1 * (NY * NZ * NODE_DW);
    const int BY0 = yi0 * (NZ * NODE_DW);
    const int BY1 = yi1 * (NZ * NODE_DW);

    const float wx1 = fx, wx0 = 1.0f - fx;
    const float wy1 = fy, wy0 = 1.0f - fy;
    const __half2 W00 = __float2half2_rn(wx0 * wy0);
    const __half2 W01 = __float2half2_rn(wx0 * wy1);
    const __half2 W10 = __float2half2_rn(wx1 * wy0);
    const __half2 W11 = __float2half2_rn(wx1 * wy1);

    const int idx = (i << 14) | (j << 7) | kk;
    const float4 g4 = *(const float4*)&gm[idx];

    float o0[4], o1[4], o2[4], o3[4];

#define H2(f) __builtin_bit_cast(__half2, f)
#pragma unroll
    for (int v = 0; v < 4; ++v) {
        const float g = (v == 0) ? g4.x : (v == 1) ? g4.y : (v == 2) ? g4.z : g4.w;
        float t = fminf(fmaxf(g * 15.0f, 0.0f), 15.0f);
        const int t0 = min((int)t, 14);
        const float ft = t - (float)t0;
        const __half2 ft2 = __float2half2_rn(ft);

        const float zf = fminf((float)(kk + v) * S_, 31.0f);
        const int z0g = (int)zf;
        const float fz = zf - (float)z0g;
        const int zi0 = z0g - z_base;
        const int zi1 = min(z0g + 1, 31) - z_base;
        const __half2 fz2 = __float2half2_rn(fz);

        const int CZ0 = zi0 * NODE_DW + (t0 << 1);
        const int CZ1 = zi1 * NODE_DW + (t0 << 1);

        // 8 corners: lo = record(t0), hi = record(t0+1), each 8B.
        const float2 a00lo = *(const float2*)&lds[AX0 + BY0 + CZ0];
        const float2 a00hi = *(const float2*)&lds[AX0 + BY0 + CZ0 + 2];
        const float2 a01lo = *(const float2*)&lds[AX0 + BY1 + CZ0];
        const float2 a01hi = *(const float2*)&lds[AX0 + BY1 + CZ0 + 2];
        const float2 a10lo = *(const float2*)&lds[AX1 + BY0 + CZ0];
        const float2 a10hi = *(const float2*)&lds[AX1 + BY0 + CZ0 + 2];
        const float2 a11lo = *(const float2*)&lds[AX1 + BY1 + CZ0];
        const float2 a11hi = *(const float2*)&lds[AX1 + BY1 + CZ0 + 2];
        const float2 b00lo = *(const float2*)&lds[AX0 + BY0 + CZ1];
        const float2 b00hi = *(const float2*)&lds[AX0 + BY0 + CZ1 + 2];
        const float2 b01lo = *(const float2*)&lds[AX0 + BY1 + CZ1];
        const float2 b01hi = *(const float2*)&lds[AX0 + BY1 + CZ1 + 2];
        const float2 b10lo = *(const float2*)&lds[AX1 + BY0 + CZ1];
        const float2 b10hi = *(const float2*)&lds[AX1 + BY0 + CZ1 + 2];
        const float2 b11lo = *(const float2*)&lds[AX1 + BY1 + CZ1];
        const float2 b11hi = *(const float2*)&lds[AX1 + BY1 + CZ1 + 2];

        // xy-accumulate z0-plane (P) and z1-plane (Q), at t0 (lo) and t0+1 (hi)
        __half2 Plo01 = __hmul2(W00, H2(a00lo.x));
        __half2 Plo23 = __hmul2(W00, H2(a00lo.y));
        __half2 Phi01 = __hmul2(W00, H2(a00hi.x));
        __half2 Phi23 = __hmul2(W00, H2(a00hi.y));
        Plo01 = __hfma2(W01, H2(a01lo.x), Plo01);
        Plo23 = __hfma2(W01, H2(a01lo.y), Plo23);
        Phi01 = __hfma2(W01, H2(a01hi.x), Phi01);
        Phi23 = __hfma2(W01, H2(a01hi.y), Phi23);
        Plo01 = __hfma2(W10, H2(a10lo.x), Plo01);
        Plo23 = __hfma2(W10, H2(a10lo.y), Plo23);
        Phi01 = __hfma2(W10, H2(a10hi.x), Phi01);
        Phi23 = __hfma2(W10, H2(a10hi.y), Phi23);
        Plo01 = __hfma2(W11, H2(a11lo.x), Plo01);
        Plo23 = __hfma2(W11, H2(a11lo.y), Plo23);
        Phi01 = __hfma2(W11, H2(a11hi.x), Phi01);
        Phi23 = __hfma2(W11, H2(a11hi.y), Phi23);

        __half2 Qlo01 = __hmul2(W00, H2(b00lo.x));
        __half2 Qlo23 = __hmul2(W00, H2(b00lo.y));
        __half2 Qhi01 = __hmul2(W00, H2(b00hi.x));
        __half2 Qhi23 = __hmul2(W00, H2(b00hi.y));
        Qlo01 = __hfma2(W01, H2(b01lo.x), Qlo01);
        Qlo23 = __hfma2(W01, H2(b01lo.y), Qlo23);
        Qhi01 = __hfma2(W01, H2(b01hi.x), Qhi01);
        Qhi23 = __hfma2(W01, H2(b01hi.y), Qhi23);
        Qlo01 = __hfma2(W10, H2(b10lo.x), Qlo01);
        Qlo23 = __hfma2(W10, H2(b10lo.y), Qlo23);
        Qhi01 = __hfma2(W10, H2(b10hi.x), Qhi01);
        Qhi23 = __hfma2(W10, H2(b10hi.y), Qhi23);
        Qlo01 = __hfma2(W11, H2(b11lo.x), Qlo01);
        Qlo23 = __hfma2(W11, H2(b11lo.y), Qlo23);
        Qhi01 = __hfma2(W11, H2(b11hi.x), Qhi01);
        Qhi23 = __hfma2(W11, H2(b11hi.y), Qhi23);

        // z blend then t lerp
        const __half2 Rlo01 = __hfma2(fz2, __hsub2(Qlo01, Plo01), Plo01);
        const __half2 Rlo23 = __hfma2(fz2, __hsub2(Qlo23, Plo23), Plo23);
        const __half2 Rhi01 = __hfma2(fz2, __hsub2(Qhi01, Phi01), Phi01);
        const __half2 Rhi23 = __hfma2(fz2, __hsub2(Qhi23, Phi23), Phi23);

        const __half2 r01 = __hfma2(ft2, __hsub2(Rhi01, Rlo01), Rlo01);
        const __half2 r23 = __hfma2(ft2, __hsub2(Rhi23, Rlo23), Rlo23);

        o0[v] = __low2float(r01);
        o1[v] = __high2float(r01);
        o2[v] = __low2float(r23);
        o3[v] = __high2float(r23);
    }
#undef H2

    float4 st;
    st.x = o0[0]; st.y = o0[1]; st.z = o0[2]; st.w = o0[3];
    *(float4*)&out[idx] = st;
    st.x = o1[0]; st.y = o1[1]; st.z = o1[2]; st.w = o1[3];
    *(float4*)&out[idx + TOTAL] = st;
    st.x = o2[0]; st.y = o2[1]; st.z = o2[2]; st.w = o2[3];
    *(float4*)&out[idx + 2 * TOTAL] = st;
    st.x = o3[0]; st.y = o3[1]; st.z = o3[2]; st.w = o3[3];
    *(float4*)&out[idx + 3 * TOTAL] = st;
}

extern "C" void kernel_launch(void* const* d_in, const int* in_sizes, int n_in,
                              void* d_out, int out_size, void* d_ws, size_t ws_size,
                              hipStream_t stream) {
    const float* bg = (const float*)d_in[0];
    const float* gm = (const float*)d_in[1];
    float* out = (float*)d_out;

    dim3 grid(2048);   // (128/8)*(128/8)*(128/16)
    dim3 block(256);
    bgrid_slice_v7<<<grid, block, 0, stream>>>(bg, gm, out);
}